// Round 4
// baseline (590.921 us; speedup 1.0000x reference)
//
#include <hip/hip_runtime.h>
#include <hip/hip_bf16.h>
#include <stdint.h>

// HydraAttention pipeline. Inputs fp32 (per reference), output fp32.
//   GEMM1: qkv = query @ w_qkv^T + b_qkv  -> q,k,v bf16
//   attn : per t: S = (q_hat k_hat^T)/8, softmax, ws = P v  (bf16, [B,T,E] layout)
//   GEMM2: out = ws @ w_out^T + b_out     -> d_out fp32
//
// T-CHUNKED: chunk count C chosen from ws_size (constant per process ->
// graph-capture safe). Footprint = 134.2 MB / C.
//
// R4 fix: ONE mfma_f32_16x16x32 per BK=32 chunk (K=32 per instruction;
// the old kk=16 second step read uninitialized LDS padding -> NaN).

typedef __attribute__((ext_vector_type(8))) short short8;   // 8 x bf16 (4 VGPR)
typedef __attribute__((ext_vector_type(4))) float floatx4;  // MFMA C/D

__device__ __forceinline__ float bf2f(short s) {
  union { unsigned u; float f; } v;
  v.u = ((unsigned)(unsigned short)s) << 16;
  return v.f;
}
__device__ __forceinline__ short f2bf(float x) {
  union { float f; unsigned u; } v; v.f = x;
  unsigned u = v.u;
  unsigned r = (u + 0x7fffu + ((u >> 16) & 1u)) >> 16;  // RNE
  return (short)r;
}
__device__ __forceinline__ short8 pack_bf8(float4 lo, float4 hi) {
  short8 r;
  r[0] = f2bf(lo.x); r[1] = f2bf(lo.y); r[2] = f2bf(lo.z); r[3] = f2bf(lo.w);
  r[4] = f2bf(hi.x); r[5] = f2bf(hi.y); r[6] = f2bf(hi.z); r[7] = f2bf(hi.w);
  return r;
}

// ---------------------------------------------------------------------------
// GEMM (B^T form): C[m,n] = sum_k A[m,k] * W[n,k] + bias[n]
// 128x128 tile, BK=32, 256 threads = 4 waves (2x2 of 64x64), 4x4 MFMAs/K-chunk.
// EPI=0: A fp32, N=3072, scatter n>>10 -> {o0,o1,o2} bf16 (q/k/v, chunk-local).
// EPI=1: A bf16 (ws), N=1024, fp32 out with chunked row remap.
// ---------------------------------------------------------------------------
template <int EPI>
__global__ __launch_bounds__(256)
void gemm_bt(const void* __restrict__ Av, const float* __restrict__ W,
             const float* __restrict__ bias, void* __restrict__ o0,
             void* __restrict__ o1, void* __restrict__ o2, int K,
             int rowbase, int tsh) {
  constexpr int KP = 40;
  __shared__ __align__(16) short As[128 * KP];
  __shared__ __align__(16) short Bs[128 * KP];

  const int tid  = threadIdx.x;
  const int lane = tid & 63, wave = tid >> 6;
  const int wm = wave >> 1, wn = wave & 1;
  const int l15 = lane & 15, quad = lane >> 4;
  const int m0 = blockIdx.y * 128, n0 = blockIdx.x * 128;
  const int srow = tid >> 2;          // 0..63 staging row
  const int sc   = (tid & 3) * 8;     // k-chunk of 8 elements

  const float* Wg = W + (size_t)(n0 + srow) * K + sc;

  floatx4 acc[4][4] = {};

  for (int k0 = 0; k0 < K; k0 += 32) {
    short8 aS0, aS1, bS0, bS1;
    if constexpr (EPI == 0) {
      const float* Ag = (const float*)Av + (size_t)(m0 + srow) * K + sc + k0;
      aS0 = pack_bf8(*(const float4*)(Ag), *(const float4*)(Ag + 4));
      aS1 = pack_bf8(*(const float4*)(Ag + (size_t)64 * K),
                     *(const float4*)(Ag + (size_t)64 * K + 4));
    } else {
      const short* Ag = (const short*)Av + (size_t)(m0 + srow) * K + sc + k0;
      aS0 = *(const short8*)(Ag);
      aS1 = *(const short8*)(Ag + (size_t)64 * K);
    }
    bS0 = pack_bf8(*(const float4*)(Wg + k0), *(const float4*)(Wg + k0 + 4));
    bS1 = pack_bf8(*(const float4*)(Wg + (size_t)64 * K + k0),
                   *(const float4*)(Wg + (size_t)64 * K + k0 + 4));
    __syncthreads();  // previous iter's LDS reads done
    *(short8*)(As + srow * KP + sc)        = aS0;
    *(short8*)(As + (srow + 64) * KP + sc) = aS1;
    *(short8*)(Bs + srow * KP + sc)        = bS0;
    *(short8*)(Bs + (srow + 64) * KP + sc) = bS1;
    __syncthreads();
    // ONE K=32 MFMA step per chunk: lane reads k = quad*8 .. quad*8+7 (< 32).
    short8 af[4], bfv[4];
#pragma unroll
    for (int i = 0; i < 4; i++)
      af[i] = *(const short8*)(As + (wm * 64 + i * 16 + l15) * KP + quad * 8);
#pragma unroll
    for (int j = 0; j < 4; j++)
      bfv[j] = *(const short8*)(Bs + (wn * 64 + j * 16 + l15) * KP + quad * 8);
#pragma unroll
    for (int i = 0; i < 4; i++)
#pragma unroll
      for (int j = 0; j < 4; j++)
        acc[i][j] = __builtin_amdgcn_mfma_f32_16x16x32_bf16(af[i], bfv[j], acc[i][j], 0, 0, 0);
  }

  // Epilogue. C/D layout: col = lane&15 (n), row = quad*4 + r (m).
#pragma unroll
  for (int i = 0; i < 4; i++) {
#pragma unroll
    for (int j = 0; j < 4; j++) {
      const int n = n0 + wn * 64 + j * 16 + l15;
      const float bv = bias[n];
#pragma unroll
      for (int r = 0; r < 4; r++) {
        const int mloc = m0 + wm * 64 + i * 16 + quad * 4 + r;
        const float v = acc[i][j][r] + bv;
        if constexpr (EPI == 0) {
          const int which = n >> 10, e = n & 1023;  // tile never straddles a 1024 boundary
          short* o = (which == 0) ? (short*)o0 : ((which == 1) ? (short*)o1 : (short*)o2);
          o[(size_t)mloc * 1024 + e] = f2bf(v);
        } else {
          const int g = ((mloc >> tsh) << 11) + rowbase + (mloc & ((1 << tsh) - 1));
          ((float*)o0)[(size_t)g * 1024 + n] = v;
        }
      }
    }
  }
}

// ---------------------------------------------------------------------------
// Attention: one block (256 thr, 4 waves) per local t'.
//   q,k,v chunk-local; per-t tiles [128][64] at t'*8192 shorts.
//   ws written chunk-local: (bz*TCH + t')*1024 + h*64 + d.
// LDS (54 KB): qs[128][72], ks[128][72]; Ps[128][136] overlays; vt[64][136];
// rsq/rsk float[128].
// ---------------------------------------------------------------------------
__global__ __launch_bounds__(256)
void attn_kernel(const short* __restrict__ qb, const short* __restrict__ kb,
                 const short* __restrict__ vb, short* __restrict__ wsb, int tch) {
  __shared__ __align__(16) char smem[55296];
  short* qs  = (short*)smem;             // [128][72]
  short* ks  = (short*)(smem + 18432);   // [128][72]
  short* Ps  = (short*)smem;             // [128][136] (after barrier, overlays qs/ks)
  short* vt  = (short*)(smem + 36864);   // [64][136]
  float* rsq = (float*)(smem + 54272);   // [128] : rsqrt(|q|^2) then 1/rowsum
  float* rsk = rsq + 128;                // [128]

  const int tp   = blockIdx.x;           // local t'
  const int tid  = threadIdx.x;
  const int lane = tid & 63, wave = tid >> 6;
  const int l15  = lane & 15, quad = lane >> 4;
  const size_t base = (size_t)tp * 8192;

  // Phase 1: load q,k into LDS; v transposed into vt.
#pragma unroll
  for (int it = 0; it < 4; it++) {
    const int c = tid + it * 256;            // chunk 0..1023
    const int row = c >> 3, c8 = (c & 7) * 8;
    uint4 qv = *(const uint4*)(qb + base + row * 64 + c8);
    uint4 kv = *(const uint4*)(kb + base + row * 64 + c8);
    *(uint4*)(qs + row * 72 + c8) = qv;
    *(uint4*)(ks + row * 72 + c8) = kv;
    short tmp[8];
    *(uint4*)tmp = *(const uint4*)(vb + base + row * 64 + c8);
#pragma unroll
    for (int j = 0; j < 8; j++) vt[(c8 + j) * 136 + row] = tmp[j];
  }
  __syncthreads();

  // Phase 2: row L2 norms.
  if (tid < 128) {
    float s = 0.f;
    for (int j = 0; j < 64; j++) { float x = bf2f(qs[tid * 72 + j]); s += x * x; }
    rsq[tid] = rsqrtf(s);
  } else {
    const int r = tid - 128;
    float s = 0.f;
    for (int j = 0; j < 64; j++) { float x = bf2f(ks[r * 72 + j]); s += x * x; }
    rsk[r] = rsqrtf(s);
  }
  __syncthreads();

  // Phase 3: S = q k^T. Each wave one 64x64 quadrant, K=64 (two K=32 steps).
  const int wm = wave >> 1, wn = wave & 1;
  floatx4 acc[4][4] = {};
#pragma unroll
  for (int kk = 0; kk < 64; kk += 32) {
    short8 af[4], bfv[4];
#pragma unroll
    for (int i = 0; i < 4; i++)
      af[i] = *(const short8*)(qs + (wm * 64 + i * 16 + l15) * 72 + kk + quad * 8);
#pragma unroll
    for (int j = 0; j < 4; j++)
      bfv[j] = *(const short8*)(ks + (wn * 64 + j * 16 + l15) * 72 + kk + quad * 8);
#pragma unroll
    for (int i = 0; i < 4; i++)
#pragma unroll
      for (int j = 0; j < 4; j++)
        acc[i][j] = __builtin_amdgcn_mfma_f32_16x16x32_bf16(af[i], bfv[j], acc[i][j], 0, 0, 0);
  }
  __syncthreads();  // all qs/ks reads done before Ps overlays them

  // Phase 4: scaled scores (cosine/8) as bf16 into Ps.
#pragma unroll
  for (int i = 0; i < 4; i++)
#pragma unroll
    for (int j = 0; j < 4; j++)
#pragma unroll
      for (int r = 0; r < 4; r++) {
        const int a    = wm * 64 + i * 16 + quad * 4 + r;
        const int bcol = wn * 64 + j * 16 + l15;
        Ps[a * 136 + bcol] = f2bf(acc[i][j][r] * rsq[a] * rsk[bcol] * 0.125f);
      }
  __syncthreads();

  // Phase 5: softmax rows; store un-normalized exp, 1/sum into rsq.
  if (tid < 128) {
    short* rowp = Ps + tid * 136;
    float mx = -1e30f;
    for (int c = 0; c < 128; c++) mx = fmaxf(mx, bf2f(rowp[c]));
    float sum = 0.f;
    for (int c = 0; c < 128; c++) {
      float p = __expf(bf2f(rowp[c]) - mx);
      sum += p;
      rowp[c] = f2bf(p);
    }
    rsq[tid] = 1.0f / sum;
  }
  __syncthreads();

  // Phase 6: ws = P v. Each wave: 32 rows, all 64 cols, K=128 (four K=32 steps).
  floatx4 acc2[2][4] = {};
#pragma unroll
  for (int kb = 0; kb < 128; kb += 32) {
    short8 af[2], bfv[4];
#pragma unroll
    for (int ti = 0; ti < 2; ti++)
      af[ti] = *(const short8*)(Ps + (wave * 32 + ti * 16 + l15) * 136 + kb + quad * 8);
#pragma unroll
    for (int tj = 0; tj < 4; tj++)
      bfv[tj] = *(const short8*)(vt + (tj * 16 + l15) * 136 + kb + quad * 8);
#pragma unroll
    for (int ti = 0; ti < 2; ti++)
#pragma unroll
      for (int tj = 0; tj < 4; tj++)
        acc2[ti][tj] = __builtin_amdgcn_mfma_f32_16x16x32_bf16(af[ti], bfv[tj], acc2[ti][tj], 0, 0, 0);
  }

  // Epilogue: normalize, write ws chunk-local in [B][TCH][E] layout.
#pragma unroll
  for (int ti = 0; ti < 2; ti++)
#pragma unroll
    for (int tj = 0; tj < 4; tj++)
#pragma unroll
      for (int r = 0; r < 4; r++) {
        const int a = wave * 32 + ti * 16 + quad * 4 + r;  // BH row
        const int d = tj * 16 + l15;                       // head dim
        const float v = acc2[ti][tj][r] * rsq[a];
        const int bz = a >> 4, h = a & 15;
        wsb[((size_t)bz * tch + tp) * 1024 + h * 64 + d] = f2bf(v);
      }
}

// ---------------------------------------------------------------------------
extern "C" void kernel_launch(void* const* d_in, const int* in_sizes, int n_in,
                              void* d_out, int out_size, void* d_ws, size_t ws_size,
                              hipStream_t stream) {
  const float* query = (const float*)d_in[0];
  // d_in[1] (key), d_in[2] (value) unused per reference semantics.
  const float* w_qkv = (const float*)d_in[3];
  const float* b_qkv = (const float*)d_in[4];
  const float* w_out = (const float*)d_in[5];
  const float* b_out = (const float*)d_in[6];
  float* out = (float*)d_out;

  // Pick smallest chunk count C (power of 2) whose ws footprint fits.
  // Footprint = 4 buffers * (16384/C rows * 1024 * 2 B) = 134217728 / C bytes.
  int C = 128;  // fallback: 1 MB footprint
  for (int c = 1; c <= 128; c <<= 1) {
    if ((size_t)(134217728 / c) <= ws_size) { C = c; break; }
  }
  const int Mc  = 16384 / C;   // rows per chunk (multiple of 128)
  const int TCH = 2048 / C;    // t's per chunk
  int tsh = 0; while ((1 << tsh) < TCH) tsh++;

  short* qbuf = (short*)d_ws;
  short* kbuf = qbuf + (size_t)Mc * 1024;
  short* vbuf = kbuf + (size_t)Mc * 1024;
  short* wsb  = vbuf + (size_t)Mc * 1024;

  for (int c = 0; c < C; c++) {
    // GEMM1: [Mc,1024] x [3072,1024]^T -> q/k/v (bf16, chunk-local)
    gemm_bt<0><<<dim3(24, Mc / 128), 256, 0, stream>>>(
        query + (size_t)c * Mc * 1024, w_qkv, b_qkv, qbuf, kbuf, vbuf, 1024, 0, 0);
    // Attention: one block per local t'
    attn_kernel<<<TCH, 256, 0, stream>>>(qbuf, kbuf, vbuf, wsb, TCH);
    // GEMM2: [Mc,1024] x [1024,1024]^T -> out rows (b, c*TCH + t') fp32
    gemm_bt<1><<<dim3(8, Mc / 128), 256, 0, stream>>>(
        wsb, w_out, b_out, out, nullptr, nullptr, 1024, c * TCH, tsh);
  }
}

// Round 5
// 477.101 us; speedup vs baseline: 1.2386x; 1.2386x over previous
//
#include <hip/hip_runtime.h>
#include <hip/hip_bf16.h>
#include <stdint.h>

// HydraAttention pipeline. Inputs fp32, output fp32.
//   cvt   : query, w_qkv, w_out  fp32 -> bf16 (hoisted out of GEMM K-loops)
//   GEMM1 : qkv = query @ w_qkv^T + b_qkv  -> q,k,v bf16   (pure-bf16, global_load_lds)
//   attn  : per t: S = (q_hat k_hat^T)/8, softmax, ws = P v (bf16, [B,T,E] layout)
//   GEMM2 : out = ws @ w_out^T + b_out     -> d_out fp32
//
// ws layout: [wqkv_bf 6.3MB][wout_bf 2MB][qbuf][kbuf][vbuf][wsb]  (wsb doubles
// as the bf16-query staging buffer: query is dead once GEMM1 has consumed it,
// and attn overwrites wsb only after that point — stream-serial, race-free).
// Chunk count C adapts to ws_size: footprint = 8.4MB + 134.2MB/C.

typedef __attribute__((ext_vector_type(8))) short short8;   // 8 x bf16 (4 VGPR)
typedef __attribute__((ext_vector_type(4))) float floatx4;  // MFMA C/D

__device__ __forceinline__ float bf2f(short s) {
  union { unsigned u; float f; } v;
  v.u = ((unsigned)(unsigned short)s) << 16;
  return v.f;
}
__device__ __forceinline__ short f2bf(float x) {
  union { float f; unsigned u; } v; v.f = x;
  unsigned u = v.u;
  unsigned r = (u + 0x7fffu + ((u >> 16) & 1u)) >> 16;  // RNE
  return (short)r;
}
__device__ __forceinline__ short8 pack_bf8(float4 lo, float4 hi) {
  short8 r;
  r[0] = f2bf(lo.x); r[1] = f2bf(lo.y); r[2] = f2bf(lo.z); r[3] = f2bf(lo.w);
  r[4] = f2bf(hi.x); r[5] = f2bf(hi.y); r[6] = f2bf(hi.z); r[7] = f2bf(hi.w);
  return r;
}

// Async global->LDS, 16 B per lane. LDS dest must equal wave-uniform base +
// lane*16 (it does for our mapping).
__device__ __forceinline__ void gl2lds16(const short* g, short* l) {
  __builtin_amdgcn_global_load_lds(
      (const __attribute__((address_space(1))) void*)g,
      (__attribute__((address_space(3))) void*)l, 16, 0, 0);
}

// ---------------------------------------------------------------------------
// fp32 -> bf16 elementwise, 8 elems/thread. n8 = n/8.
// ---------------------------------------------------------------------------
__global__ __launch_bounds__(256)
void cvt_bf16(const float* __restrict__ in, short* __restrict__ out, int n8) {
  const int i = blockIdx.x * 256 + threadIdx.x;
  if (i < n8) {
    float4 a = ((const float4*)in)[2 * i];
    float4 b = ((const float4*)in)[2 * i + 1];
    ((short8*)out)[i] = pack_bf8(a, b);
  }
}

// ---------------------------------------------------------------------------
// Pure-bf16 GEMM (B^T form): C[m,n] = sum_k A[m,k]*W[n,k] + bias[n]
// m97 structure: 128x128 tile, BK=32, global_load_lds dwordx4 staging into
// unpadded LDS [128][32], 2-barrier K-loop, 4 waves (2x2), 16 MFMA/iter.
// EPI=0: N=3072, scatter n>>10 -> {o0,o1,o2} bf16 (q/k/v).
// EPI=1: N=1024, fp32 out with chunked row remap.
// ---------------------------------------------------------------------------
template <int EPI>
__global__ __launch_bounds__(256)
void gemm_bf(const short* __restrict__ A, const short* __restrict__ W,
             const float* __restrict__ bias, void* __restrict__ o0,
             void* __restrict__ o1, void* __restrict__ o2, int K,
             int rowbase, int tsh) {
  __shared__ __align__(16) short As[128 * 32];
  __shared__ __align__(16) short Bs[128 * 32];

  const int tid  = threadIdx.x;
  const int lane = tid & 63, wave = tid >> 6;
  const int wm = wave >> 1, wn = wave & 1;
  const int l15 = lane & 15, quad = lane >> 4;
  const int m0 = blockIdx.y * 128, n0 = blockIdx.x * 128;

  // Staging: wave w covers rows [w*32, w*32+32) in two 16-row wave-calls.
  // Lane l -> row base + l/4, col (l&3)*8. LDS byte dest = uniform + lane*16.
  const int srow = wave * 32 + (lane >> 2);
  const int scol = (lane & 3) * 8;
  const short* Ag = A + (size_t)(m0 + srow) * K + scol;
  const short* Wg = W + (size_t)(n0 + srow) * K + scol;
  short* AsD = As + srow * 32 + scol;
  short* BsD = Bs + srow * 32 + scol;

  floatx4 acc[4][4] = {};

  for (int k0 = 0; k0 < K; k0 += 32) {
    __syncthreads();                       // prev iter's fragment reads done
    gl2lds16(Ag + k0, AsD);
    gl2lds16(Ag + k0 + (size_t)16 * K, AsD + 16 * 32);
    gl2lds16(Wg + k0, BsD);
    gl2lds16(Wg + k0 + (size_t)16 * K, BsD + 16 * 32);
    __syncthreads();                       // drains vmcnt(0): loads landed
    short8 af[4], bfv[4];
#pragma unroll
    for (int i = 0; i < 4; i++)
      af[i] = *(const short8*)(As + (wm * 64 + i * 16 + l15) * 32 + quad * 8);
#pragma unroll
    for (int j = 0; j < 4; j++)
      bfv[j] = *(const short8*)(Bs + (wn * 64 + j * 16 + l15) * 32 + quad * 8);
#pragma unroll
    for (int i = 0; i < 4; i++)
#pragma unroll
      for (int j = 0; j < 4; j++)
        acc[i][j] = __builtin_amdgcn_mfma_f32_16x16x32_bf16(af[i], bfv[j], acc[i][j], 0, 0, 0);
  }

  // Epilogue. C/D layout: col = lane&15 (n), row = quad*4 + r (m).
#pragma unroll
  for (int i = 0; i < 4; i++) {
#pragma unroll
    for (int j = 0; j < 4; j++) {
      const int n = n0 + wn * 64 + j * 16 + l15;
      const float bv = bias[n];
#pragma unroll
      for (int r = 0; r < 4; r++) {
        const int mloc = m0 + wm * 64 + i * 16 + quad * 4 + r;
        const float v = acc[i][j][r] + bv;
        if constexpr (EPI == 0) {
          const int which = n >> 10, e = n & 1023;
          short* o = (which == 0) ? (short*)o0 : ((which == 1) ? (short*)o1 : (short*)o2);
          o[(size_t)mloc * 1024 + e] = f2bf(v);
        } else {
          const int g = ((mloc >> tsh) << 11) + rowbase + (mloc & ((1 << tsh) - 1));
          ((float*)o0)[(size_t)g * 1024 + n] = v;
        }
      }
    }
  }
}

// ---------------------------------------------------------------------------
// Attention: one block (256 thr, 4 waves) per local t'. (unchanged from R4)
// ---------------------------------------------------------------------------
__global__ __launch_bounds__(256)
void attn_kernel(const short* __restrict__ qb, const short* __restrict__ kb,
                 const short* __restrict__ vb, short* __restrict__ wsb, int tch) {
  __shared__ __align__(16) char smem[55296];
  short* qs  = (short*)smem;             // [128][72]
  short* ks  = (short*)(smem + 18432);   // [128][72]
  short* Ps  = (short*)smem;             // [128][136] (overlays qs/ks after S)
  short* vt  = (short*)(smem + 36864);   // [64][136]
  float* rsq = (float*)(smem + 54272);   // [128]
  float* rsk = rsq + 128;                // [128]

  const int tp   = blockIdx.x;
  const int tid  = threadIdx.x;
  const int lane = tid & 63, wave = tid >> 6;
  const int l15  = lane & 15, quad = lane >> 4;
  const size_t base = (size_t)tp * 8192;

#pragma unroll
  for (int it = 0; it < 4; it++) {
    const int c = tid + it * 256;
    const int row = c >> 3, c8 = (c & 7) * 8;
    uint4 qv = *(const uint4*)(qb + base + row * 64 + c8);
    uint4 kv = *(const uint4*)(kb + base + row * 64 + c8);
    *(uint4*)(qs + row * 72 + c8) = qv;
    *(uint4*)(ks + row * 72 + c8) = kv;
    short tmp[8];
    *(uint4*)tmp = *(const uint4*)(vb + base + row * 64 + c8);
#pragma unroll
    for (int j = 0; j < 8; j++) vt[(c8 + j) * 136 + row] = tmp[j];
  }
  __syncthreads();

  if (tid < 128) {
    float s = 0.f;
    for (int j = 0; j < 64; j++) { float x = bf2f(qs[tid * 72 + j]); s += x * x; }
    rsq[tid] = rsqrtf(s);
  } else {
    const int r = tid - 128;
    float s = 0.f;
    for (int j = 0; j < 64; j++) { float x = bf2f(ks[r * 72 + j]); s += x * x; }
    rsk[r] = rsqrtf(s);
  }
  __syncthreads();

  const int wm = wave >> 1, wn = wave & 1;
  floatx4 acc[4][4] = {};
#pragma unroll
  for (int kk = 0; kk < 64; kk += 32) {
    short8 af[4], bfv[4];
#pragma unroll
    for (int i = 0; i < 4; i++)
      af[i] = *(const short8*)(qs + (wm * 64 + i * 16 + l15) * 72 + kk + quad * 8);
#pragma unroll
    for (int j = 0; j < 4; j++)
      bfv[j] = *(const short8*)(ks + (wn * 64 + j * 16 + l15) * 72 + kk + quad * 8);
#pragma unroll
    for (int i = 0; i < 4; i++)
#pragma unroll
      for (int j = 0; j < 4; j++)
        acc[i][j] = __builtin_amdgcn_mfma_f32_16x16x32_bf16(af[i], bfv[j], acc[i][j], 0, 0, 0);
  }
  __syncthreads();

#pragma unroll
  for (int i = 0; i < 4; i++)
#pragma unroll
    for (int j = 0; j < 4; j++)
#pragma unroll
      for (int r = 0; r < 4; r++) {
        const int a    = wm * 64 + i * 16 + quad * 4 + r;
        const int bcol = wn * 64 + j * 16 + l15;
        Ps[a * 136 + bcol] = f2bf(acc[i][j][r] * rsq[a] * rsk[bcol] * 0.125f);
      }
  __syncthreads();

  if (tid < 128) {
    short* rowp = Ps + tid * 136;
    float mx = -1e30f;
    for (int c = 0; c < 128; c++) mx = fmaxf(mx, bf2f(rowp[c]));
    float sum = 0.f;
    for (int c = 0; c < 128; c++) {
      float p = __expf(bf2f(rowp[c]) - mx);
      sum += p;
      rowp[c] = f2bf(p);
    }
    rsq[tid] = 1.0f / sum;
  }
  __syncthreads();

  floatx4 acc2[2][4] = {};
#pragma unroll
  for (int kb = 0; kb < 128; kb += 32) {
    short8 af[2], bfv[4];
#pragma unroll
    for (int ti = 0; ti < 2; ti++)
      af[ti] = *(const short8*)(Ps + (wave * 32 + ti * 16 + l15) * 136 + kb + quad * 8);
#pragma unroll
    for (int tj = 0; tj < 4; tj++)
      bfv[tj] = *(const short8*)(vt + (tj * 16 + l15) * 136 + kb + quad * 8);
#pragma unroll
    for (int ti = 0; ti < 2; ti++)
#pragma unroll
      for (int tj = 0; tj < 4; tj++)
        acc2[ti][tj] = __builtin_amdgcn_mfma_f32_16x16x32_bf16(af[ti], bfv[tj], acc2[ti][tj], 0, 0, 0);
  }

#pragma unroll
  for (int ti = 0; ti < 2; ti++)
#pragma unroll
    for (int tj = 0; tj < 4; tj++)
#pragma unroll
      for (int r = 0; r < 4; r++) {
        const int a = wave * 32 + ti * 16 + quad * 4 + r;
        const int d = tj * 16 + l15;
        const float v = acc2[ti][tj][r] * rsq[a];
        const int bz = a >> 4, h = a & 15;
        wsb[((size_t)bz * tch + tp) * 1024 + h * 64 + d] = f2bf(v);
      }
}

// ---------------------------------------------------------------------------
extern "C" void kernel_launch(void* const* d_in, const int* in_sizes, int n_in,
                              void* d_out, int out_size, void* d_ws, size_t ws_size,
                              hipStream_t stream) {
  const float* query = (const float*)d_in[0];
  // d_in[1] (key), d_in[2] (value) unused per reference semantics.
  const float* w_qkv = (const float*)d_in[3];
  const float* b_qkv = (const float*)d_in[4];
  const float* w_out = (const float*)d_in[5];
  const float* b_out = (const float*)d_in[6];
  float* out = (float*)d_out;

  // Chunk count C: footprint = 8.4MB weights + 4*(16384/C)*2048 B.
  int C = 128;
  for (int c = 1; c <= 128; c <<= 1) {
    if ((size_t)(8388608 + 134217728 / c) <= ws_size) { C = c; break; }
  }
  const int Mc  = 16384 / C;   // rows per chunk (multiple of 128)
  const int TCH = 2048 / C;    // t's per chunk
  int tsh = 0; while ((1 << tsh) < TCH) tsh++;

  short* wqkvb = (short*)d_ws;            // 3072*1024 bf16
  short* woutb = wqkvb + 3145728;         // 1024*1024 bf16
  short* qbuf  = woutb + 1048576;
  short* kbuf  = qbuf + (size_t)Mc * 1024;
  short* vbuf  = kbuf + (size_t)Mc * 1024;
  short* wsb   = vbuf + (size_t)Mc * 1024;   // overlay: bf16 query chunk, then attn out

  cvt_bf16<<<3145728 / 8 / 256, 256, 0, stream>>>(w_qkv, wqkvb, 3145728 / 8);
  cvt_bf16<<<1048576 / 8 / 256, 256, 0, stream>>>(w_out, woutb, 1048576 / 8);

  for (int c = 0; c < C; c++) {
    const int n8 = Mc * 1024 / 8;
    cvt_bf16<<<(n8 + 255) / 256, 256, 0, stream>>>(query + (size_t)c * Mc * 1024, wsb, n8);
    gemm_bf<0><<<dim3(24, Mc / 128), 256, 0, stream>>>(
        wsb, wqkvb, b_qkv, qbuf, kbuf, vbuf, 1024, 0, 0);
    attn_kernel<<<TCH, 256, 0, stream>>>(qbuf, kbuf, vbuf, wsb, TCH);
    gemm_bf<1><<<dim3(8, Mc / 128), 256, 0, stream>>>(
        wsb, woutb, b_out, out, nullptr, nullptr, 1024, c * TCH, tsh);
  }
}